// Round 4
// baseline (551.377 us; speedup 1.0000x reference)
//
#include <hip/hip_runtime.h>
#include <cstddef>
#include <cstdint>

#define BATCH 32
#define SEQ 2048
#define DM 1024

typedef __attribute__((ext_vector_type(8))) _Float16 half8v;
typedef __attribute__((ext_vector_type(4))) float f32x4;

// tanh(x) = 1 - 2/(e^{2x}+1); saturates to +-1 correctly for |x| large
__device__ __forceinline__ float tanh_fast(float x) {
    float e = __expf(2.0f * x);
    return 1.0f - 2.0f / (e + 1.0f);
}

// ---------------- init ----------------
__global__ __launch_bounds__(256) void init_kernel(float* __restrict__ scores,
                                                   float* __restrict__ context) {
    int idx = blockIdx.x * 256 + threadIdx.x;
    if (idx < BATCH * SEQ) scores[idx] = 0.f;
    if (idx < BATCH * DM) context[idx] = 0.f;
}

// ---------------- q projection ----------------
__global__ __launch_bounds__(256) void qproj_kernel(const float* __restrict__ query,
                                                    const float* __restrict__ Wq_w,
                                                    const float* __restrict__ Wq_b,
                                                    float* __restrict__ q_out) {
    int b = blockIdx.x;
    int tid = threadIdx.x;
    __shared__ float qs[DM];
    for (int i = tid; i < DM; i += 256) qs[i] = query[b * DM + i];
    __syncthreads();
    for (int d = tid; d < DM; d += 256) {
        const float4* w4 = reinterpret_cast<const float4*>(Wq_w + (size_t)d * DM);
        float acc = Wq_b[d];
#pragma unroll 4
        for (int e4 = 0; e4 < DM / 4; ++e4) {
            float4 w = w4[e4];
            acc += w.x * qs[e4 * 4 + 0] + w.y * qs[e4 * 4 + 1] +
                   w.z * qs[e4 * 4 + 2] + w.w * qs[e4 * 4 + 3];
        }
        q_out[b * DM + d] = acc;
    }
}

// ---------------- scores: fp16 2-term split MFMA GEMM, 2-phase pipelined ----------------
#define BM 128
#define BN 256
#define BK 32
#define NT (DM / BK)   // 32 K-steps

__global__ __launch_bounds__(256, 2) void scores_kernel(const float* __restrict__ keys,
                                                        const float* __restrict__ Wk_w,
                                                        const float* __restrict__ Wk_b,
                                                        const float* __restrict__ q,
                                                        const float* __restrict__ v_w,
                                                        float* __restrict__ scores) {
    // Double-buffered, K-subtiled [buf][kc][row][8] fp16; 16B rows = conflict-minimal
    // for both ds_write_b128 and ds_read_b128. Total exactly 64 KB -> 2 blocks/CU.
    __shared__ _Float16 AhS[2][4][BM][8];   // 16 KB
    __shared__ _Float16 AlS[2][4][BM][8];   // 16 KB
    __shared__ _Float16 BhS[2][4][BN][8];   // 32 KB

    // XCD-aware order: 2048 blocks = 8 XCDs x 256 slots (bijective). nchunk-minor
    // within XCD: the 4 blocks sharing an A-tile are adjacent slots -> co-resident
    // on one XCD -> A fetched from HBM once, 3 L2 hits.
    const unsigned bid = blockIdx.x;
    const unsigned L = (bid & 7u) * 256u + (bid >> 3);
    const int mtile = (int)(L >> 2);       // 0..511
    const int nchunk = (int)(L & 3u);      // 0..3
    const int m0 = mtile * BM;
    const int n0 = nchunk * BN;
    const int b = m0 >> 11;

    const int t = threadIdx.x;
    const int w = t >> 6, l = t & 63;
    const int wm = w >> 1, wn = w & 1;     // 2x2 waves; wave tile 64m x 128n
    const int lr = l & 15, lg = l >> 4;

    // A staging: 2 threads/row, 16 k-elems each. B staging: 1 thread/row, 32 k.
    const int ra = t >> 1, ha = t & 1;
    const float* Ap = keys + (size_t)(m0 + ra) * DM + ha * 16;
    const float* Bp = Wk_w + (size_t)(n0 + t) * DM;

    float4 asA[4], asB[4];   // two A staging sets (2-deep pipeline)
    float4 bs[8];            // one B staging set (1-deep; B is L2-hot)

    f32x4 acc[4][8];
#pragma unroll
    for (int mi = 0; mi < 4; ++mi)
#pragma unroll
        for (int ni = 0; ni < 8; ++ni)
#pragma unroll
            for (int c = 0; c < 4; ++c) acc[mi][ni][c] = 0.f;

    union H8 { _Float16 f[8]; half8v v; };

    // ---- staging macros (all indices compile-time static) ----
#define LOAD_A(dst, kt)                                                          \
    {                                                                            \
        _Pragma("unroll") for (int j = 0; j < 4; ++j)                            \
            dst[j] = *reinterpret_cast<const float4*>(Ap + (kt) * BK + 4 * j);   \
    }
#define LOAD_B(kt)                                                               \
    {                                                                            \
        _Pragma("unroll") for (int j = 0; j < 8; ++j)                            \
            bs[j] = *reinterpret_cast<const float4*>(Bp + (kt) * BK + 4 * j);    \
    }
#define STAGE(bufi, aset)                                                        \
    {                                                                            \
        H8 ah[2], al[2], bh[4];                                                  \
        _Pragma("unroll") for (int j = 0; j < 4; ++j) {                          \
            const float* fa = reinterpret_cast<const float*>(&aset[j]);          \
            _Pragma("unroll") for (int c = 0; c < 4; ++c) {                      \
                int idx = 4 * j + c;                                             \
                _Float16 hi = (_Float16)fa[c];                                   \
                _Float16 lo = (_Float16)(fa[c] - (float)hi);                     \
                ah[idx >> 3].f[idx & 7] = hi;                                    \
                al[idx >> 3].f[idx & 7] = lo;                                    \
            }                                                                    \
        }                                                                        \
        _Pragma("unroll") for (int j = 0; j < 8; ++j) {                          \
            const float* fb = reinterpret_cast<const float*>(&bs[j]);            \
            _Pragma("unroll") for (int c = 0; c < 4; ++c) {                      \
                int idx = 4 * j + c;                                             \
                bh[idx >> 3].f[idx & 7] = (_Float16)fb[c];                       \
            }                                                                    \
        }                                                                        \
        *reinterpret_cast<half8v*>(&AhS[bufi][2 * ha][ra][0]) = ah[0].v;         \
        *reinterpret_cast<half8v*>(&AhS[bufi][2 * ha + 1][ra][0]) = ah[1].v;     \
        *reinterpret_cast<half8v*>(&AlS[bufi][2 * ha][ra][0]) = al[0].v;         \
        *reinterpret_cast<half8v*>(&AlS[bufi][2 * ha + 1][ra][0]) = al[1].v;     \
        _Pragma("unroll") for (int kc = 0; kc < 4; ++kc)                         \
            *reinterpret_cast<half8v*>(&BhS[bufi][kc][t][0]) = bh[kc].v;         \
    }
#define COMPUTE(bufi)                                                            \
    {                                                                            \
        half8v bhv[8];                                                           \
        _Pragma("unroll") for (int ni = 0; ni < 8; ++ni)                         \
            bhv[ni] = *reinterpret_cast<const half8v*>(                          \
                &BhS[bufi][lg][wn * 128 + ni * 16 + lr][0]);                     \
        __builtin_amdgcn_s_setprio(1);                                           \
        _Pragma("unroll") for (int mi = 0; mi < 4; ++mi) {                       \
            const int row = wm * 64 + mi * 16 + lr;                              \
            half8v ahv = *reinterpret_cast<const half8v*>(&AhS[bufi][lg][row][0]); \
            half8v alv = *reinterpret_cast<const half8v*>(&AlS[bufi][lg][row][0]); \
            _Pragma("unroll") for (int ni = 0; ni < 8; ++ni) {                   \
                acc[mi][ni] = __builtin_amdgcn_mfma_f32_16x16x32_f16(            \
                    ahv, bhv[ni], acc[mi][ni], 0, 0, 0);                         \
                acc[mi][ni] = __builtin_amdgcn_mfma_f32_16x16x32_f16(            \
                    alv, bhv[ni], acc[mi][ni], 0, 0, 0);                         \
            }                                                                    \
        }                                                                        \
        __builtin_amdgcn_s_setprio(0);                                           \
    }

    // ---- prologue: stage tile 0 into buf0; issue A(1) ----
    LOAD_A(asA, 0);
    LOAD_B(0);
    STAGE(0, asA);
    LOAD_A(asB, 1);
    __syncthreads();

    // ---- main loop, 2x unrolled (even iter: compute buf0/issue asA; odd: buf1/asB)
    for (int tt = 0; tt < NT; tt += 2) {
        // even iteration (tile tt, buf0): B first (older -> cvt waits only B),
        // then A(tt+2) stays in flight across ~2 phases.
        if (tt + 1 < NT) LOAD_B(tt + 1);
        if (tt + 2 < NT) LOAD_A(asA, tt + 2);
        COMPUTE(0);
        if (tt + 1 < NT) STAGE(1, asB);
        __syncthreads();

        // odd iteration (tile tt+1, buf1)
        if (tt + 2 < NT) LOAD_B(tt + 2);
        if (tt + 3 < NT) LOAD_A(asB, tt + 3);
        COMPUTE(1);
        if (tt + 2 < NT) STAGE(0, asA);
        __syncthreads();
    }

    // ---- epilogue: tanh * v_w, reduce over this block's 256 n-dims ----
    float qb[8], vw[8];
#pragma unroll
    for (int ni = 0; ni < 8; ++ni) {
        int n = n0 + wn * 128 + ni * 16 + lr;
        qb[ni] = q[b * DM + n] + Wk_b[n];
        vw[ni] = v_w[n];
    }
#pragma unroll
    for (int mi = 0; mi < 4; ++mi) {
#pragma unroll
        for (int rg = 0; rg < 4; ++rg) {
            float p = 0.f;
#pragma unroll
            for (int ni = 0; ni < 8; ++ni) {
                float val = acc[mi][ni][rg] + qb[ni];
                p += tanh_fast(val) * vw[ni];
            }
#pragma unroll
            for (int off = 8; off >= 1; off >>= 1) p += __shfl_xor(p, off, 16);
            if (lr == 0)
                atomicAdd(&scores[m0 + wm * 64 + mi * 16 + lg * 4 + rg], p);
        }
    }
#undef LOAD_A
#undef LOAD_B
#undef STAGE
#undef COMPUTE
}

// ---------------- softmax over S per batch row ----------------
__global__ __launch_bounds__(256) void softmax_kernel(const float* __restrict__ scores,
                                                      float* __restrict__ attn) {
    int b = blockIdx.x;
    int tid = threadIdx.x;
    __shared__ float redm[4];
    __shared__ float reds[4];
    float v[8];
    float mx = -1e30f;
#pragma unroll
    for (int i = 0; i < 8; ++i) {
        v[i] = scores[b * SEQ + i * 256 + tid];
        mx = fmaxf(mx, v[i]);
    }
#pragma unroll
    for (int off = 32; off >= 1; off >>= 1) mx = fmaxf(mx, __shfl_xor(mx, off));
    int wid = tid >> 6;
    if ((tid & 63) == 0) redm[wid] = mx;
    __syncthreads();
    mx = fmaxf(fmaxf(redm[0], redm[1]), fmaxf(redm[2], redm[3]));
    float sum = 0.f;
#pragma unroll
    for (int i = 0; i < 8; ++i) {
        v[i] = expf(v[i] - mx);
        sum += v[i];
    }
#pragma unroll
    for (int off = 32; off >= 1; off >>= 1) sum += __shfl_xor(sum, off);
    if ((tid & 63) == 0) reds[wid] = sum;
    __syncthreads();
    sum = reds[0] + reds[1] + reds[2] + reds[3];
    float inv = 1.f / sum;
#pragma unroll
    for (int i = 0; i < 8; ++i) attn[b * SEQ + i * 256 + tid] = v[i] * inv;
}

// ---------------- context = attn @ keys ----------------
__global__ __launch_bounds__(256) void context_kernel(const float* __restrict__ keys,
                                                      const float* __restrict__ attn,
                                                      float* __restrict__ context) {
    int id = blockIdx.x;           // 32 b * 4 dchunk * 8 schunk = 1024 blocks
    int schunk = id & 7;
    int dchunk = (id >> 3) & 3;
    int b = id >> 5;
    int tid = threadIdx.x;
    int d = dchunk * 256 + tid;
    __shared__ float a_s[256];
    a_s[tid] = attn[b * SEQ + schunk * 256 + tid];
    __syncthreads();
    const float* kp = keys + ((size_t)b * SEQ + (size_t)schunk * 256) * DM + d;
    float acc = 0.f;
#pragma unroll 8
    for (int s = 0; s < 256; ++s) acc += a_s[s] * kp[(size_t)s * DM];
    atomicAdd(&context[b * DM + d], acc);
}

extern "C" void kernel_launch(void* const* d_in, const int* in_sizes, int n_in,
                              void* d_out, int out_size, void* d_ws, size_t ws_size,
                              hipStream_t stream) {
    const float* query = (const float*)d_in[0];
    const float* keys  = (const float*)d_in[1];
    const float* Wq_w  = (const float*)d_in[2];
    const float* Wq_b  = (const float*)d_in[3];
    const float* Wk_w  = (const float*)d_in[4];
    const float* Wk_b  = (const float*)d_in[5];
    const float* v_w   = (const float*)d_in[6];
    // d_in[7] = v_b: additive constant on all scores -> cancels exactly in softmax.

    float* context = (float*)d_out;              // [32][1024]
    float* attn    = context + BATCH * DM;       // [32][2048]

    float* q      = (float*)d_ws;                // [32][1024]
    float* scores = q + BATCH * DM;              // [32][2048]

    hipLaunchKernelGGL(init_kernel, dim3(256), dim3(256), 0, stream, scores, context);
    hipLaunchKernelGGL(qproj_kernel, dim3(BATCH), dim3(256), 0, stream,
                       query, Wq_w, Wq_b, q);
    hipLaunchKernelGGL(scores_kernel, dim3((BATCH * SEQ / BM) * (DM / BN)), dim3(256), 0, stream,
                       keys, Wk_w, Wk_b, q, v_w, scores);
    hipLaunchKernelGGL(softmax_kernel, dim3(BATCH), dim3(256), 0, stream, scores, attn);
    hipLaunchKernelGGL(context_kernel, dim3(1024), dim3(256), 0, stream, keys, attn, context);
}

// Round 6
// 317.799 us; speedup vs baseline: 1.7350x; 1.7350x over previous
//
#include <hip/hip_runtime.h>
#include <cstddef>
#include <cstdint>

#define BATCH 32
#define SEQ 2048
#define DM 1024

typedef __attribute__((ext_vector_type(8))) _Float16 half8v;
typedef __attribute__((ext_vector_type(4))) _Float16 half4v;
typedef __attribute__((ext_vector_type(4))) float f32x4;

// Persistent device-global scratch (fully rewritten every launch; no stale-state deps)
__device__ _Float16 g_B16[DM * DM];            // Wk_w pre-converted to fp16 (2 MB)
__device__ float g_q[BATCH * DM];              // q projection (128 KB)
__device__ float g_sp[8][BATCH * SEQ];         // scores partials: slot = nchunk*2 + wn

// tanh(x) = 1 - 2/(e^{2x}+1); saturates to +-1 correctly for |x| large
__device__ __forceinline__ float tanh_fast(float x) {
    float e = __expf(2.0f * x);
    return 1.0f - 2.0f / (e + 1.0f);
}

__device__ __forceinline__ void gload16(const void* g, void* l) {
    __builtin_amdgcn_global_load_lds((__attribute__((address_space(1))) void*)g,
                                     (__attribute__((address_space(3))) void*)l, 16, 0, 0);
}

// ---------------- convert Wk_w -> fp16 (once per launch, ~6 MB traffic) ----------------
__global__ __launch_bounds__(256) void convb_kernel(const float* __restrict__ Wk_w) {
    int i = blockIdx.x * 256 + threadIdx.x;            // 262144 float4 groups
    float4 w = reinterpret_cast<const float4*>(Wk_w)[i];
    half4v h;
    h[0] = (_Float16)w.x; h[1] = (_Float16)w.y; h[2] = (_Float16)w.z; h[3] = (_Float16)w.w;
    *reinterpret_cast<half4v*>(&g_B16[(size_t)i * 4]) = h;
}

// ---------------- init: zero context (atomically accumulated) ----------------
__global__ __launch_bounds__(256) void init_kernel(float* __restrict__ context) {
    int idx = blockIdx.x * 256 + threadIdx.x;
    if (idx < BATCH * DM) context[idx] = 0.f;
}

// ---------------- q projection: block per output d; Wq read once total ----------------
__global__ __launch_bounds__(256) void qproj_kernel(const float* __restrict__ query,
                                                    const float* __restrict__ Wq_w,
                                                    const float* __restrict__ Wq_b) {
    int d = blockIdx.x;
    int t = threadIdx.x;
    __shared__ float wrow[DM];
    __shared__ float part[8][32];
    reinterpret_cast<float4*>(wrow)[t] =
        reinterpret_cast<const float4*>(Wq_w + (size_t)d * DM)[t];
    __syncthreads();
    int b = t & 31, seg = t >> 5;
    const float4* qp = reinterpret_cast<const float4*>(query + b * DM + seg * 128);
    const float4* wp = reinterpret_cast<const float4*>(wrow + seg * 128);
    float acc = 0.f;
#pragma unroll
    for (int i = 0; i < 32; ++i) {
        float4 qv = qp[i];
        float4 wv = wp[i];
        acc += qv.x * wv.x + qv.y * wv.y + qv.z * wv.z + qv.w * wv.w;
    }
    part[seg][b] = acc;
    __syncthreads();
    if (t < 32) {
        float s = Wq_b[d];
#pragma unroll
        for (int g = 0; g < 8; ++g) s += part[g][t];
        g_q[t * DM + d] = s;
    }
}

// ---------------- scores: single-pass fp16 MFMA GEMM, DMA-staged B ----------------
#define BM 128
#define BN 256
#define BK 32
#define NT (DM / BK)   // 32 K-steps

__global__ __launch_bounds__(256, 2) void scores_kernel(const float* __restrict__ keys,
                                                        const float* __restrict__ Wk_b,
                                                        const float* __restrict__ v_w) {
    // K-subtiled [buf][kc][row][8] fp16, 16B rows; B region layout matches the
    // linear lane x 16B pattern global_load_lds writes. Total 48 KB.
    __shared__ _Float16 AhS[2][4][BM][8];   // 16 KB
    __shared__ _Float16 BhS[2][4][BN][8];   // 32 KB

    // XCD-aware order: 2048 blocks = 8 XCDs x 256 slots (bijective); nchunk-minor
    // so the 4 blocks sharing an A-tile are co-resident on one XCD (A read once).
    const unsigned bid = blockIdx.x;
    const unsigned L = (bid & 7u) * 256u + (bid >> 3);
    const int mtile = (int)(L >> 2);       // 0..511
    const int nchunk = (int)(L & 3u);      // 0..3
    const int m0 = mtile * BM;
    const int n0 = nchunk * BN;
    const int b = m0 >> 11;

    const int t = threadIdx.x;
    const int w = t >> 6, l = t & 63;
    const int wm = w >> 1, wn = w & 1;     // 2x2 waves; wave tile 64m x 128n
    const int lr = l & 15, lg = l >> 4;

    // A staging: 2 threads/row, 16 k-elems each.
    const int ra = t >> 1, ha = t & 1;
    const float* Ap = keys + (size_t)(m0 + ra) * DM + ha * 16;

    float4 asA[4], asB[4];   // two A staging sets (load 1.5 tiles ahead)

    f32x4 acc[4][8];
#pragma unroll
    for (int mi = 0; mi < 4; ++mi)
#pragma unroll
        for (int ni = 0; ni < 8; ++ni)
#pragma unroll
            for (int c = 0; c < 4; ++c) acc[mi][ni][c] = 0.f;

#define LOAD_A(dst, kt)                                                          \
    {                                                                            \
        _Pragma("unroll") for (int j = 0; j < 4; ++j)                            \
            dst[j] = *reinterpret_cast<const float4*>(Ap + (kt) * BK + 4 * j);   \
    }
    // wave w DMAs kc=w plane: 4 issues x 64 rows x 16B
#define ISSUE_B(kt, bufi)                                                        \
    {                                                                            \
        const _Float16* gb = &g_B16[(size_t)(n0 + l) * DM + (kt) * BK + w * 8];  \
        _Pragma("unroll") for (int rg = 0; rg < 4; ++rg)                         \
            gload16(gb + (size_t)rg * 64 * DM, &BhS[bufi][w][rg * 64][0]);       \
    }
#define STAGE_A(bufi, aset)                                                      \
    {                                                                            \
        union H8 { _Float16 f[8]; half8v v; } ah[2];                             \
        _Pragma("unroll") for (int j = 0; j < 4; ++j) {                          \
            const float* fa = reinterpret_cast<const float*>(&aset[j]);          \
            _Pragma("unroll") for (int c = 0; c < 4; ++c) {                      \
                int idx = 4 * j + c;                                             \
                ah[idx >> 3].f[idx & 7] = (_Float16)fa[c];                       \
            }                                                                    \
        }                                                                        \
        *reinterpret_cast<half8v*>(&AhS[bufi][2 * ha][ra][0]) = ah[0].v;         \
        *reinterpret_cast<half8v*>(&AhS[bufi][2 * ha + 1][ra][0]) = ah[1].v;     \
    }
#define COMPUTE(bufi)                                                            \
    {                                                                            \
        half8v bhv[8];                                                           \
        _Pragma("unroll") for (int ni = 0; ni < 8; ++ni)                         \
            bhv[ni] = *reinterpret_cast<const half8v*>(                          \
                &BhS[bufi][lg][wn * 128 + ni * 16 + lr][0]);                     \
        __builtin_amdgcn_s_setprio(1);                                           \
        _Pragma("unroll") for (int mi = 0; mi < 4; ++mi) {                       \
            half8v ahv = *reinterpret_cast<const half8v*>(                       \
                &AhS[bufi][lg][wm * 64 + mi * 16 + lr][0]);                      \
            _Pragma("unroll") for (int ni = 0; ni < 8; ++ni)                     \
                acc[mi][ni] = __builtin_amdgcn_mfma_f32_16x16x32_f16(            \
                    ahv, bhv[ni], acc[mi][ni], 0, 0, 0);                         \
        }                                                                        \
        __builtin_amdgcn_s_setprio(0);                                          \
    }

    // prologue: tile 0 into buf0 (B by DMA, A by reg+cvt); A(1) in flight
    ISSUE_B(0, 0);
    LOAD_A(asA, 0);
    STAGE_A(0, asA);
    LOAD_A(asB, 1);
    __syncthreads();   // drains B(0) DMA

    for (int tt = 0; tt < NT; tt += 2) {
        if (tt + 1 < NT) ISSUE_B(tt + 1, 1);
        if (tt + 2 < NT) LOAD_A(asA, tt + 2);
        COMPUTE(0);
        if (tt + 1 < NT) STAGE_A(1, asB);
        __syncthreads();

        if (tt + 2 < NT) ISSUE_B(tt + 2, 0);
        if (tt + 3 < NT) LOAD_A(asB, tt + 3);
        COMPUTE(1);
        if (tt + 2 < NT) STAGE_A(0, asA);
        __syncthreads();
    }

    // epilogue: tanh * v_w, reduce over this wave's 128 n-cols.
    // Slot = nchunk*2 + wn: exactly ONE writer per (slot,row) -> deterministic.
    float qb[8], vw[8];
#pragma unroll
    for (int ni = 0; ni < 8; ++ni) {
        int n = n0 + wn * 128 + ni * 16 + lr;
        qb[ni] = g_q[b * DM + n] + Wk_b[n];
        vw[ni] = v_w[n];
    }
#pragma unroll
    for (int mi = 0; mi < 4; ++mi) {
#pragma unroll
        for (int rg = 0; rg < 4; ++rg) {
            float p = 0.f;
#pragma unroll
            for (int ni = 0; ni < 8; ++ni) {
                float val = acc[mi][ni][rg] + qb[ni];
                p += tanh_fast(val) * vw[ni];
            }
#pragma unroll
            for (int off = 8; off >= 1; off >>= 1) p += __shfl_xor(p, off, 16);
            if (lr == 0)
                g_sp[nchunk * 2 + wn][m0 + wm * 64 + mi * 16 + lg * 4 + rg] = p;
        }
    }
#undef LOAD_A
#undef ISSUE_B
#undef STAGE_A
#undef COMPUTE
}

// ---------------- softmax over S per batch row (sums the 8 partial slots) --------
__global__ __launch_bounds__(256) void softmax_kernel(float* __restrict__ attn) {
    int b = blockIdx.x;
    int tid = threadIdx.x;
    __shared__ float redm[4];
    __shared__ float reds[4];
    float v[8];
    float mx = -1e30f;
#pragma unroll
    for (int i = 0; i < 8; ++i) {
        int idx = b * SEQ + i * 256 + tid;
        float s = 0.f;
#pragma unroll
        for (int pslot = 0; pslot < 8; ++pslot) s += g_sp[pslot][idx];
        v[i] = s;
        mx = fmaxf(mx, v[i]);
    }
#pragma unroll
    for (int off = 32; off >= 1; off >>= 1) mx = fmaxf(mx, __shfl_xor(mx, off));
    int wid = tid >> 6;
    if ((tid & 63) == 0) redm[wid] = mx;
    __syncthreads();
    mx = fmaxf(fmaxf(redm[0], redm[1]), fmaxf(redm[2], redm[3]));
    float sum = 0.f;
#pragma unroll
    for (int i = 0; i < 8; ++i) {
        v[i] = expf(v[i] - mx);
        sum += v[i];
    }
#pragma unroll
    for (int off = 32; off >= 1; off >>= 1) sum += __shfl_xor(sum, off);
    if ((tid & 63) == 0) reds[wid] = sum;
    __syncthreads();
    sum = reds[0] + reds[1] + reds[2] + reds[3];
    float inv = 1.f / sum;
#pragma unroll
    for (int i = 0; i < 8; ++i) attn[b * SEQ + i * 256 + tid] = v[i] * inv;
}

// ---------------- context = attn @ keys (coalesced float4 rows) ----------------
__global__ __launch_bounds__(256) void context_kernel(const float* __restrict__ keys,
                                                      const float* __restrict__ attn,
                                                      float* __restrict__ context) {
    int id = blockIdx.x;              // 32 b x 16 schunk = 512 blocks
    int schunk = id & 15;
    int b = id >> 4;
    int tid = threadIdx.x;
    __shared__ float a_s[128];
    if (tid < 128) a_s[tid] = attn[b * SEQ + schunk * 128 + tid];
    __syncthreads();
    const float4* kp =
        reinterpret_cast<const float4*>(keys + ((size_t)b * SEQ + schunk * 128) * DM) + tid;
    float4 acc = {0.f, 0.f, 0.f, 0.f};
#pragma unroll 4
    for (int s = 0; s < 128; ++s) {
        float4 kv = kp[(size_t)s * (DM / 4)];
        float a = a_s[s];
        acc.x += a * kv.x; acc.y += a * kv.y; acc.z += a * kv.z; acc.w += a * kv.w;
    }
    atomicAdd(&context[b * DM + tid * 4 + 0], acc.x);
    atomicAdd(&context[b * DM + tid * 4 + 1], acc.y);
    atomicAdd(&context[b * DM + tid * 4 + 2], acc.z);
    atomicAdd(&context[b * DM + tid * 4 + 3], acc.w);
}

extern "C" void kernel_launch(void* const* d_in, const int* in_sizes, int n_in,
                              void* d_out, int out_size, void* d_ws, size_t ws_size,
                              hipStream_t stream) {
    const float* query = (const float*)d_in[0];
    const float* keys  = (const float*)d_in[1];
    const float* Wq_w  = (const float*)d_in[2];
    const float* Wq_b  = (const float*)d_in[3];
    const float* Wk_w  = (const float*)d_in[4];
    const float* Wk_b  = (const float*)d_in[5];
    const float* v_w   = (const float*)d_in[6];
    // d_in[7] = v_b: additive constant on all scores -> cancels exactly in softmax.

    float* context = (float*)d_out;              // [32][1024]
    float* attn    = context + BATCH * DM;       // [32][2048]

    hipLaunchKernelGGL(convb_kernel, dim3(1024), dim3(256), 0, stream, Wk_w);
    hipLaunchKernelGGL(init_kernel, dim3(128), dim3(256), 0, stream, context);
    hipLaunchKernelGGL(qproj_kernel, dim3(DM), dim3(256), 0, stream, query, Wq_w, Wq_b);
    hipLaunchKernelGGL(scores_kernel, dim3((BATCH * SEQ / BM) * (DM / BN)), dim3(256), 0, stream,
                       keys, Wk_b, v_w);
    hipLaunchKernelGGL(softmax_kernel, dim3(BATCH), dim3(256), 0, stream, attn);
    hipLaunchKernelGGL(context_kernel, dim3(512), dim3(256), 0, stream, keys, attn, context);
}